// Round 11
// baseline (684.256 us; speedup 1.0000x reference)
//
#include <hip/hip_runtime.h>
#include <cstdint>
#include <cstddef>

#define BATCH   4
#define SEQ     8192
#define DREC    1024
#define CHUNK   64
#define NCHUNK  128              // SEQ/CHUNK
#define M_TOT   (BATCH*SEQ)      // 32768
#define N_AIV   3072

#define BM 256
#define BN 256
#define BK 32
#define NBUF 4                   // quad-buffered LDS, prefetch depth 3

typedef _Float16 half8 __attribute__((ext_vector_type(8)));
typedef _Float16 half4 __attribute__((ext_vector_type(4)));
typedef float   floatx4 __attribute__((ext_vector_type(4)));

#define LOG2E   1.4426950408889634f
#define NLOG2EPS 33.219281f      /* -log2(1e-10) */

// NOTE (r5): hardware log2 builtin is __builtin_amdgcn_logf (v_log_f32 = log2),
// per __clang_hip_math.h's __log2f. __builtin_amdgcn_log2f does not exist.

__device__ __forceinline__ void gl_lds16(const void* g, void* l) {
    __builtin_amdgcn_global_load_lds(
        (const __attribute__((address_space(1))) void*)g,
        (__attribute__((address_space(3))) void*)l, 16, 0, 0);
}

__device__ __forceinline__ float fast_sigmoid(float z) {
    float e = __builtin_amdgcn_exp2f(-LOG2E * z);
    return __builtin_amdgcn_rcpf(1.f + e);
}

// ---------------------------------------------------------------------------
// C[M,N] = A_f16[M,K] @ B[K,N] (+bias), pure-f16 MFMA.
// 256x256 tile, BK=32, 512 threads (8 waves, 2Mx4N, 128x64 out each).
// LDS: 4 x 32KB K-tile buffers (128 KiB). Counted-vmcnt pipeline (T3+T4):
//   prologue stages tiles 0..2; each iter: wait vmcnt(8), raw s_barrier,
//   stage tile t+3 (buffer read-complete at t-1), ds_read frags, 32 MFMA
//   under setprio (T5). vmcnt never drains to 0 until the tail.
// LDS swizzle: 16B slot s of row r holds k-group g = s ^ ((r>>1)&3)
//   -> 2-way bank aliasing only (free, m136).
// Measured: G1 235.8 us / 874 TF, G2 ~86 us (r2/r8). BYTE-IDENTICAL since r2.
// ---------------------------------------------------------------------------
template <bool F16_OUT>
__global__ __launch_bounds__(512, 2) void gemm_ff(
    const _Float16* __restrict__ A, int lda,
    const _Float16* __restrict__ BT, int ldb,
    void* __restrict__ Cv, int ldc, int K,
    const float* __restrict__ bias)
{
    __shared__ __align__(16) _Float16 sm[NBUF * 16384];   // 128 KiB

    const int tid  = threadIdx.x;
    const int lane = tid & 63;
    const int wave = tid >> 6;            // 0..7

    // XCD-chunked bijective block swizzle (nwg % 8 == 0 for both GEMMs)
    const int nwg = gridDim.x * gridDim.y;
    int lin = blockIdx.y * gridDim.x + blockIdx.x;
    {
        const int cpx = nwg >> 3;
        lin = (lin & 7) * cpx + (lin >> 3);
    }
    const int bx = lin % gridDim.x;
    const int by = lin / gridDim.x;
    const int bm = by * BM;
    const int bn = bx * BN;
    const int wm = (wave >> 2) * 128;     // 0 / 128
    const int wn = (wave & 3) * 64;       // 0/64/128/192

    floatx4 acc[8][4];
    const floatx4 z4 = {0.f, 0.f, 0.f, 0.f};
    #pragma unroll
    for (int i = 0; i < 8; ++i)
        #pragma unroll
        for (int j = 0; j < 4; ++j) acc[i][j] = z4;

    const int o0 = tid * 16, o1 = o0 + 8192;
    const int r0 = o0 >> 6, s0 = (o0 >> 4) & 3;
    const int r1 = o1 >> 6, s1 = (o1 >> 4) & 3;
    const int g0 = (s0 ^ ((r0 >> 1) & 3)) * 8;
    const int g1 = (s1 ^ ((r1 >> 1) & 3)) * 8;
    const size_t aRow0 = (size_t)(bm + r0) * lda;
    const size_t aRow1 = (size_t)(bm + r1) * lda;
    const size_t bRow0 = (size_t)(bn + r0) * ldb;
    const size_t bRow1 = (size_t)(bn + r1) * ldb;

    auto stage = [&](int t) {
        const int k0 = t * BK;
        char* base = (char*)sm + (t & (NBUF - 1)) * 32768;
        gl_lds16(A  + aRow0 + k0 + g0, base + o0);
        gl_lds16(A  + aRow1 + k0 + g1, base + o1);
        gl_lds16(BT + bRow0 + k0 + g0, base + 16384 + o0);
        gl_lds16(BT + bRow1 + k0 + g1, base + 16384 + o1);
    };

    const int fm = lane & 15;
    const int fq = lane >> 4;
    const int m0 = wm + fm;
    const int n0 = wn + fm;
    const int aoff0 = m0 * BK + ((fq ^ ((m0 >> 1) & 3)) << 3);
    const int boff0 = n0 * BK + ((fq ^ ((n0 >> 1) & 3)) << 3);

    const int NT = K / BK;
    stage(0);
    if (NT > 1) stage(1);
    if (NT > 2) stage(2);

    for (int t = 0; t < NT; ++t) {
        const int rem = NT - 1 - t;
        if (rem >= 2)      asm volatile("s_waitcnt vmcnt(8)" ::: "memory");
        else if (rem == 1) asm volatile("s_waitcnt vmcnt(4)" ::: "memory");
        else               asm volatile("s_waitcnt vmcnt(0)" ::: "memory");
        __builtin_amdgcn_s_barrier();
        __builtin_amdgcn_sched_barrier(0);

        if (t + 3 < NT) stage(t + 3);

        const _Float16* sA = sm + (t & (NBUF - 1)) * 16384;
        const _Float16* sB = sA + 8192;
        half8 ah[8], bh[4];
        #pragma unroll
        for (int i = 0; i < 8; ++i) ah[i] = *(const half8*)&sA[aoff0 + i * 16 * BK];
        #pragma unroll
        for (int j = 0; j < 4; ++j) bh[j] = *(const half8*)&sB[boff0 + j * 16 * BK];

        __builtin_amdgcn_s_setprio(1);
        #pragma unroll
        for (int i = 0; i < 8; ++i)
            #pragma unroll
            for (int j = 0; j < 4; ++j)
                acc[i][j] = __builtin_amdgcn_mfma_f32_16x16x32_f16(
                    ah[i], bh[j], acc[i][j], 0, 0, 0);
        __builtin_amdgcn_s_setprio(0);
        __builtin_amdgcn_sched_barrier(0);
    }

    const int er = (lane >> 4) * 4;
    const int ec = lane & 15;
    #pragma unroll
    for (int j = 0; j < 4; ++j) {
        int col = bn + wn + j * 16 + ec;
        float bj = (!F16_OUT && bias) ? bias[col] : 0.f;
        #pragma unroll
        for (int i = 0; i < 8; ++i) {
            int rowb = bm + wm + i * 16 + er;
            #pragma unroll
            for (int r = 0; r < 4; ++r) {
                if (F16_OUT)
                    ((_Float16*)Cv)[(size_t)(rowb + r) * ldc + col] =
                        (_Float16)acc[i][j][r];
                else
                    ((float*)Cv)[(size_t)(rowb + r) * ldc + col] =
                        acc[i][j][r] + bj;
            }
        }
    }
}

// ---------------------------------------------------------------------------
// x fp32 -> f16, grid-stride, 8 elems/thread/iter.
// ---------------------------------------------------------------------------
__global__ __launch_bounds__(256) void cvt_to_f16(
    const float* __restrict__ src, _Float16* __restrict__ dst)
{
    const size_t stride = (size_t)gridDim.x * 256 * 8;
    size_t i = ((size_t)blockIdx.x * 256 + threadIdx.x) * 8;
    #pragma unroll 2
    for (; i < (size_t)M_TOT * DREC; i += stride) {
        float4 a = *(const float4*)(src + i);
        float4 b = *(const float4*)(src + i + 4);
        half8 h;
        h[0] = (_Float16)a.x; h[1] = (_Float16)a.y;
        h[2] = (_Float16)a.z; h[3] = (_Float16)a.w;
        h[4] = (_Float16)b.x; h[5] = (_Float16)b.y;
        h[6] = (_Float16)b.z; h[7] = (_Float16)b.w;
        *(half8*)(dst + i) = h;
    }
}

// ---------------------------------------------------------------------------
// W[K,N] fp32 -> T[N,K] f16 (transpose + convert), 32x32 LDS tiles.
// ---------------------------------------------------------------------------
__global__ __launch_bounds__(256) void transpose_cvt(
    const float* __restrict__ W, int K, int N, _Float16* __restrict__ T)
{
    __shared__ float tile[32][33];
    const int k0 = blockIdx.y * 32, n0 = blockIdx.x * 32;
    const int tx = threadIdx.x & 31, ty = threadIdx.x >> 5;  // ty 0..7
    #pragma unroll
    for (int r = 0; r < 32; r += 8)
        tile[ty + r][tx] = W[(size_t)(k0 + ty + r) * N + n0 + tx];
    __syncthreads();
    #pragma unroll
    for (int r = 0; r < 32; r += 8)
        T[(size_t)(n0 + ty + r) * K + k0 + tx] = (_Float16)tile[tx][ty + r];
}

// row loader for the d8 scans: 3 x 16 B per row (a, i, v segments)
#define LDROW8(ap,ip,vv,T) { const _Float16* q = base + (size_t)(T) * 3072;   \
    ap = *(const half8*)q; ip = *(const half8*)(q + 1024);                    \
    vv = *(const half8*)(q + 2048); }

// ---------------------------------------------------------------------------
// Pass A (fused gates + intra scan, summaries only).
// One thread per (b,chunk,d8) -> 8 channels, half8 (16 B) loads (G13:
// halves VMEM transaction count vs the r4 d4/half4 version; wave-loads
// become fully dense 1024 B lines). Distance-2 software pipeline; scan in
// log2 domain: cl2 = sum log2(a); 1/max(exp2(cl2),1e-10) = exp2(min(-cl2,33.22)).
// 65536 threads, 256 blocks.
// ---------------------------------------------------------------------------
__global__ __launch_bounds__(256) void scan_chunks(
    const _Float16* __restrict__ aivh, const float* __restrict__ decay_bias,
    float* __restrict__ ctd, float* __restrict__ cfs)
{
    int g  = blockIdx.x * 256 + threadIdx.x;   // < 4*128*128
    int d8 = g & 127;
    int bc = g >> 7;                            // b*128 + chunk

    const _Float16* base =
        aivh + ((size_t)bc * CHUNK) * 3072 + (size_t)d8 * 8;
    float db[8];
    {
        float4 lo = *(const float4*)&decay_bias[d8 * 8];
        float4 hi = *(const float4*)&decay_bias[d8 * 8 + 4];
        db[0]=lo.x; db[1]=lo.y; db[2]=lo.z; db[3]=lo.w;
        db[4]=hi.x; db[5]=hi.y; db[6]=hi.z; db[7]=hi.w;
    }

    float cl2[8] = {0,0,0,0,0,0,0,0}, cw[8] = {0,0,0,0,0,0,0,0};

    auto step = [&](half8 ap, half8 ip, half8 vv) {
        #pragma unroll
        for (int e = 0; e < 8; ++e) {
            float a  = fast_sigmoid((float)ap[e] + db[e]);
            float ii = fast_sigmoid((float)ip[e]);
            float s  = __builtin_amdgcn_sqrtf(fmaxf(1.f - a * a, 1e-8f))
                       * (ii * (float)vv[e]);
            cl2[e] += __builtin_amdgcn_logf(fmaxf(a, 1e-10f));
            float inv = __builtin_amdgcn_exp2f(fminf(-cl2[e], NLOG2EPS));
            cw[e] += s * inv;
        }
    };

    half8 a0, i0, v0, a1, i1, v1;
    LDROW8(a0, i0, v0, 0);
    LDROW8(a1, i1, v1, 1);
    for (int t = 0; t < CHUNK - 2; t += 2) {
        half8 a2, i2, v2, a3, i3, v3;
        LDROW8(a2, i2, v2, t + 2);
        LDROW8(a3, i3, v3, t + 3);
        step(a0, i0, v0);
        step(a1, i1, v1);
        a0 = a2; i0 = i2; v0 = v2;
        a1 = a3; i1 = i3; v1 = v3;
    }
    step(a0, i0, v0);
    step(a1, i1, v1);

    size_t so = (size_t)bc * 1024 + (size_t)d8 * 8;
    #pragma unroll
    for (int h = 0; h < 2; ++h) {
        float4 td, fs;
        td.x = __builtin_amdgcn_exp2f(cl2[h*4+0]);
        td.y = __builtin_amdgcn_exp2f(cl2[h*4+1]);
        td.z = __builtin_amdgcn_exp2f(cl2[h*4+2]);
        td.w = __builtin_amdgcn_exp2f(cl2[h*4+3]);
        fs.x = td.x * cw[h*4+0]; fs.y = td.y * cw[h*4+1];
        fs.z = td.z * cw[h*4+2]; fs.w = td.w * cw[h*4+3];
        *(float4*)&ctd[so + h*4] = td;
        *(float4*)&cfs[so + h*4] = fs;
    }
}

// ---------------------------------------------------------------------------
// Inter-chunk scan: per (b,d), 128 chunk steps, log2 domain, distance-2
// prefetch. 64-thread blocks to spread the 4096 threads over 64 CUs.
// ---------------------------------------------------------------------------
__global__ __launch_bounds__(64) void scan_inter(
    const float* __restrict__ ctd, const float* __restrict__ cfs,
    float* __restrict__ incoming)
{
    int g = blockIdx.x * 64 + threadIdx.x;   // < 4*1024
    int d = g & 1023;
    int b = g >> 10;

    const size_t base = (size_t)b * NCHUNK * 1024 + (size_t)d;
    float cum2 = 0.f, cwc = 0.f;
    float pccd = 1.f, pcwc = 0.f;

    float t0 = ctd[base], f0 = cfs[base];
    float t1 = ctd[base + 1024], f1 = cfs[base + 1024];
    for (int n = 0; n < NCHUNK - 2; n += 2) {
        float t2 = ctd[base + (size_t)(n + 2) * 1024];
        float f2 = cfs[base + (size_t)(n + 2) * 1024];
        float t3 = ctd[base + (size_t)(n + 3) * 1024];
        float f3 = cfs[base + (size_t)(n + 3) * 1024];

        incoming[base + (size_t)n * 1024] = (n == 0) ? 0.f : pccd * pcwc;
        cum2 += __builtin_amdgcn_logf(fmaxf(t0, 1e-10f));
        float ccd = __builtin_amdgcn_exp2f(cum2);
        cwc += f0 * __builtin_amdgcn_exp2f(fminf(-cum2, NLOG2EPS));
        pccd = ccd; pcwc = cwc;

        incoming[base + (size_t)(n + 1) * 1024] = pccd * pcwc;
        cum2 += __builtin_amdgcn_logf(fmaxf(t1, 1e-10f));
        ccd = __builtin_amdgcn_exp2f(cum2);
        cwc += f1 * __builtin_amdgcn_exp2f(fminf(-cum2, NLOG2EPS));
        pccd = ccd; pcwc = cwc;

        t0 = t2; f0 = f2; t1 = t3; f1 = f3;
    }
    incoming[base + (size_t)(NCHUNK - 2) * 1024] = pccd * pcwc;
    cum2 += __builtin_amdgcn_logf(fmaxf(t0, 1e-10f));
    pccd = __builtin_amdgcn_exp2f(cum2);
    cwc += f0 * __builtin_amdgcn_exp2f(fminf(-cum2, NLOG2EPS));
    pcwc = cwc;
    incoming[base + (size_t)(NCHUNK - 1) * 1024] = pccd * pcwc;
}

// ---------------------------------------------------------------------------
// Pass C (fused gates + intra scan + combine), d8/half8 like Pass A;
// writes h = cd*(cw+inc) as half8 (16 B/lane) into hb[M_TOT,1024].
// ---------------------------------------------------------------------------
__global__ __launch_bounds__(256) void scan_apply(
    const _Float16* __restrict__ aivh, const float* __restrict__ decay_bias,
    const float* __restrict__ incoming, _Float16* __restrict__ hb)
{
    int g  = blockIdx.x * 256 + threadIdx.x;   // < 4*128*128
    int d8 = g & 127;
    int bc = g >> 7;

    const _Float16* base =
        aivh + ((size_t)bc * CHUNK) * 3072 + (size_t)d8 * 8;
    _Float16* hbase = hb + ((size_t)bc * CHUNK) * 1024 + (size_t)d8 * 8;
    float db[8], inc[8];
    {
        float4 lo = *(const float4*)&decay_bias[d8 * 8];
        float4 hi = *(const float4*)&decay_bias[d8 * 8 + 4];
        db[0]=lo.x; db[1]=lo.y; db[2]=lo.z; db[3]=lo.w;
        db[4]=hi.x; db[5]=hi.y; db[6]=hi.z; db[7]=hi.w;
        size_t io = (size_t)bc * 1024 + (size_t)d8 * 8;
        float4 il = *(const float4*)&incoming[io];
        float4 ih = *(const float4*)&incoming[io + 4];
        inc[0]=il.x; inc[1]=il.y; inc[2]=il.z; inc[3]=il.w;
        inc[4]=ih.x; inc[5]=ih.y; inc[6]=ih.z; inc[7]=ih.w;
    }

    float cl2[8] = {0,0,0,0,0,0,0,0}, cw[8] = {0,0,0,0,0,0,0,0};

    auto step = [&](half8 ap, half8 ip, half8 vv, int t) {
        half8 h;
        #pragma unroll
        for (int e = 0; e < 8; ++e) {
            float a  = fast_sigmoid((float)ap[e] + db[e]);
            float ii = fast_sigmoid((float)ip[e]);
            float s  = __builtin_amdgcn_sqrtf(fmaxf(1.f - a * a, 1e-8f))
                       * (ii * (float)vv[e]);
            cl2[e] += __builtin_amdgcn_logf(fmaxf(a, 1e-10f));
            float inv = __builtin_amdgcn_exp2f(fminf(-cl2[e], NLOG2EPS));
            cw[e] += s * inv;
            float cd = __builtin_amdgcn_exp2f(cl2[e]);
            h[e] = (_Float16)(cd * (cw[e] + inc[e]));
        }
        *(half8*)&hbase[(size_t)t * 1024] = h;
    };

    half8 a0, i0, v0, a1, i1, v1;
    LDROW8(a0, i0, v0, 0);
    LDROW8(a1, i1, v1, 1);
    for (int t = 0; t < CHUNK - 2; t += 2) {
        half8 a2, i2, v2, a3, i3, v3;
        LDROW8(a2, i2, v2, t + 2);
        LDROW8(a3, i3, v3, t + 3);
        step(a0, i0, v0, t);
        step(a1, i1, v1, t + 1);
        a0 = a2; i0 = i2; v0 = v2;
        a1 = a3; i1 = i3; v1 = v3;
    }
    step(a0, i0, v0, CHUNK - 2);
    step(a1, i1, v1, CHUNK - 1);
}

// ---------------------------------------------------------------------------
extern "C" void kernel_launch(void* const* d_in, const int* in_sizes, int n_in,
                              void* d_out, int out_size, void* d_ws, size_t ws_size,
                              hipStream_t stream)
{
    const float* x          = (const float*)d_in[0];  // (4,8192,1024)
    const float* W_aiv      = (const float*)d_in[1];  // (1024,3072)
    const float* decay_bias = (const float*)d_in[2];  // (1024,)
    const float* W_mix      = (const float*)d_in[3];  // (1024,1024)
    const float* b_mix      = (const float*)d_in[4];  // (1024,)
    float* out = (float*)d_out;                       // (4,8192,1024) fp32

    _Float16* aivh  = (_Float16*)d_ws;
    _Float16* xh    = aivh + (size_t)M_TOT * N_AIV;
    float* ctd      = (float*)(xh + (size_t)M_TOT * DREC);
    float* cfs      = ctd + (size_t)BATCH * NCHUNK * DREC;
    float* incoming = cfs + (size_t)BATCH * NCHUNK * DREC;
    _Float16* wT    = (_Float16*)(incoming + (size_t)BATCH * NCHUNK * DREC);
    _Float16* mT    = wT + (size_t)N_AIV * DREC;
    _Float16* hb    = xh;   // alias: xh dead after GEMM1

    // 0) conversions (x -> f16; weights -> transposed f16)
    cvt_to_f16<<<2048, 256, 0, stream>>>(x, xh);
    {
        dim3 g1(N_AIV / 32, DREC / 32);
        transpose_cvt<<<g1, 256, 0, stream>>>(W_aiv, DREC, N_AIV, wT);
        dim3 g2(DREC / 32, DREC / 32);
        transpose_cvt<<<g2, 256, 0, stream>>>(W_mix, DREC, DREC, mT);
    }
    // 1) aivh = xh @ W_aiv   (pure-f16 MFMA, f16 output)
    {
        dim3 grid(N_AIV / BN, M_TOT / BM);   // (12, 128) = 1536 blocks
        gemm_ff<true><<<grid, 512, 0, stream>>>(xh, DREC, wT, DREC,
                                                aivh, N_AIV, DREC, nullptr);
    }
    // 2) fused gates + intra scan -> chunk summaries (d8, 256 blocks)
    scan_chunks<<<(BATCH * NCHUNK * 128) / 256, 256, 0, stream>>>(
        aivh, decay_bias, ctd, cfs);
    // 3) inter-chunk scan
    scan_inter<<<(BATCH * DREC) / 64, 64, 0, stream>>>(ctd, cfs, incoming);
    // 4) fused gates + intra scan + combine -> hb (f16, compact; d8)
    scan_apply<<<(BATCH * NCHUNK * 128) / 256, 256, 0, stream>>>(
        aivh, decay_bias, incoming, hb);
    // 5) out = hb @ W_mix + b_mix  (pure-f16 MFMA, fp32 output)
    {
        dim3 grid(DREC / BN, M_TOT / BM);    // (4, 128) = 512 blocks
        gemm_ff<false><<<grid, 512, 0, stream>>>(hb, DREC, mT, DREC,
                                                 out, DREC, DREC, b_mix);
    }
}

// Round 12
// 657.351 us; speedup vs baseline: 1.0409x; 1.0409x over previous
//
#include <hip/hip_runtime.h>
#include <cstdint>
#include <cstddef>

#define BATCH   4
#define SEQ     8192
#define DREC    1024
#define CHUNK   64
#define NCHUNK  128              // SEQ/CHUNK
#define M_TOT   (BATCH*SEQ)      // 32768
#define N_AIV   3072

#define BM 256
#define BN 256
#define BK 32
#define NBUF 4                   // quad-buffered LDS, prefetch depth 3

typedef _Float16 half8 __attribute__((ext_vector_type(8)));
typedef _Float16 half4 __attribute__((ext_vector_type(4)));
typedef float   floatx4 __attribute__((ext_vector_type(4)));

#define LOG2E   1.4426950408889634f
#define NLOG2EPS 33.219281f      /* -log2(1e-10) */

// NOTE (r5): hardware log2 builtin is __builtin_amdgcn_logf (v_log_f32 = log2),
// per __clang_hip_math.h's __log2f. __builtin_amdgcn_log2f does not exist.
// NOTE (r11): d8 scans (1 wave/SIMD) regressed +21us vs d4 — scans are
// TLP-limited, not transaction-limited. Keep d4 (r8-measured, 662.7us total).

__device__ __forceinline__ void gl_lds16(const void* g, void* l) {
    __builtin_amdgcn_global_load_lds(
        (const __attribute__((address_space(1))) void*)g,
        (__attribute__((address_space(3))) void*)l, 16, 0, 0);
}

__device__ __forceinline__ float fast_sigmoid(float z) {
    float e = __builtin_amdgcn_exp2f(-LOG2E * z);
    return __builtin_amdgcn_rcpf(1.f + e);
}

// ---------------------------------------------------------------------------
// C[M,N] = A_f16[M,K] @ B[K,N] (+bias), pure-f16 MFMA.
// 256x256 tile, BK=32, 512 threads (8 waves, 2Mx4N, 128x64 out each).
// LDS: 4 x 32KB K-tile buffers (128 KiB), counted-vmcnt quad-buffer pipeline.
// r12: K-loop phase-split (m201-style): per K-tile two {read||stage ->
// barrier -> lgkm(0) -> 16 MFMA} phases. A-frags read once (P1) and held in
// regs across both phases; B read 2+2; stage split A-half(P1)/B-half(P2).
// vmcnt ladder unchanged (4 loads/tile, 12 outstanding steady-state).
// Hazards: stage(t+3) writes buf[(t-1)&3]; all reads of that buffer
// completed >= 2 barriers earlier (audited r12). All barriers uniform.
// Prev measured (1-phase body): G1 235.8us/874TF MfmaUtil 39%, G2 ~86us.
// ---------------------------------------------------------------------------
template <bool F16_OUT>
__global__ __launch_bounds__(512, 2) void gemm_ff(
    const _Float16* __restrict__ A, int lda,
    const _Float16* __restrict__ BT, int ldb,
    void* __restrict__ Cv, int ldc, int K,
    const float* __restrict__ bias)
{
    __shared__ __align__(16) _Float16 sm[NBUF * 16384];   // 128 KiB

    const int tid  = threadIdx.x;
    const int lane = tid & 63;
    const int wave = tid >> 6;            // 0..7

    // XCD-chunked bijective block swizzle (nwg % 8 == 0 for both GEMMs)
    const int nwg = gridDim.x * gridDim.y;
    int lin = blockIdx.y * gridDim.x + blockIdx.x;
    {
        const int cpx = nwg >> 3;
        lin = (lin & 7) * cpx + (lin >> 3);
    }
    const int bx = lin % gridDim.x;
    const int by = lin / gridDim.x;
    const int bm = by * BM;
    const int bn = bx * BN;
    const int wm = (wave >> 2) * 128;     // 0 / 128
    const int wn = (wave & 3) * 64;       // 0/64/128/192

    floatx4 acc[8][4];
    const floatx4 z4 = {0.f, 0.f, 0.f, 0.f};
    #pragma unroll
    for (int i = 0; i < 8; ++i)
        #pragma unroll
        for (int j = 0; j < 4; ++j) acc[i][j] = z4;

    const int o0 = tid * 16, o1 = o0 + 8192;
    const int r0 = o0 >> 6, s0 = (o0 >> 4) & 3;
    const int r1 = o1 >> 6, s1 = (o1 >> 4) & 3;
    const int g0 = (s0 ^ ((r0 >> 1) & 3)) * 8;
    const int g1 = (s1 ^ ((r1 >> 1) & 3)) * 8;
    const size_t aRow0 = (size_t)(bm + r0) * lda;
    const size_t aRow1 = (size_t)(bm + r1) * lda;
    const size_t bRow0 = (size_t)(bn + r0) * ldb;
    const size_t bRow1 = (size_t)(bn + r1) * ldb;

    auto stageA = [&](int t) {
        const int k0 = t * BK;
        char* base = (char*)sm + (t & (NBUF - 1)) * 32768;
        gl_lds16(A + aRow0 + k0 + g0, base + o0);
        gl_lds16(A + aRow1 + k0 + g1, base + o1);
    };
    auto stageB = [&](int t) {
        const int k0 = t * BK;
        char* base = (char*)sm + (t & (NBUF - 1)) * 32768;
        gl_lds16(BT + bRow0 + k0 + g0, base + 16384 + o0);
        gl_lds16(BT + bRow1 + k0 + g1, base + 16384 + o1);
    };

    const int fm = lane & 15;
    const int fq = lane >> 4;
    const int m0 = wm + fm;
    const int n0 = wn + fm;
    const int aoff0 = m0 * BK + ((fq ^ ((m0 >> 1) & 3)) << 3);
    const int boff0 = n0 * BK + ((fq ^ ((n0 >> 1) & 3)) << 3);

    const int NT = K / BK;
    stageA(0); stageB(0);
    if (NT > 1) { stageA(1); stageB(1); }
    if (NT > 2) { stageA(2); stageB(2); }

    for (int t = 0; t < NT; ++t) {
        const int rem = NT - 1 - t;
        if (rem >= 2)      asm volatile("s_waitcnt vmcnt(8)" ::: "memory");
        else if (rem == 1) asm volatile("s_waitcnt vmcnt(4)" ::: "memory");
        else               asm volatile("s_waitcnt vmcnt(0)" ::: "memory");
        __builtin_amdgcn_s_barrier();            // B0: tile t visible to all
        __builtin_amdgcn_sched_barrier(0);

        const _Float16* sA = sm + (t & (NBUF - 1)) * 16384;
        const _Float16* sB = sA + 8192;

        // ---- P1: ds_read A(8) + B(n0,n1); stage A-half of t+3 ----
        half8 ah[8], bh01[2];
        #pragma unroll
        for (int i = 0; i < 8; ++i) ah[i] = *(const half8*)&sA[aoff0 + i * 16 * BK];
        bh01[0] = *(const half8*)&sB[boff0 + 0 * 16 * BK];
        bh01[1] = *(const half8*)&sB[boff0 + 1 * 16 * BK];
        if (t + 3 < NT) stageA(t + 3);
        __builtin_amdgcn_s_barrier();            // B1: role-split boundary
        asm volatile("s_waitcnt lgkmcnt(0)" ::: "memory");
        __builtin_amdgcn_sched_barrier(0);

        // P2's B-reads issued early: latency hides under P1's MFMA cluster.
        half8 bh23[2];
        bh23[0] = *(const half8*)&sB[boff0 + 2 * 16 * BK];
        bh23[1] = *(const half8*)&sB[boff0 + 3 * 16 * BK];

        __builtin_amdgcn_s_setprio(1);
        #pragma unroll
        for (int i = 0; i < 8; ++i) {
            acc[i][0] = __builtin_amdgcn_mfma_f32_16x16x32_f16(ah[i], bh01[0], acc[i][0], 0, 0, 0);
            acc[i][1] = __builtin_amdgcn_mfma_f32_16x16x32_f16(ah[i], bh01[1], acc[i][1], 0, 0, 0);
        }
        __builtin_amdgcn_s_setprio(0);
        __builtin_amdgcn_sched_barrier(0);

        // ---- P2: stage B-half of t+3 ----
        if (t + 3 < NT) stageB(t + 3);
        __builtin_amdgcn_s_barrier();            // B2
        asm volatile("s_waitcnt lgkmcnt(0)" ::: "memory");
        __builtin_amdgcn_sched_barrier(0);

        __builtin_amdgcn_s_setprio(1);
        #pragma unroll
        for (int i = 0; i < 8; ++i) {
            acc[i][2] = __builtin_amdgcn_mfma_f32_16x16x32_f16(ah[i], bh23[0], acc[i][2], 0, 0, 0);
            acc[i][3] = __builtin_amdgcn_mfma_f32_16x16x32_f16(ah[i], bh23[1], acc[i][3], 0, 0, 0);
        }
        __builtin_amdgcn_s_setprio(0);
        __builtin_amdgcn_sched_barrier(0);
    }

    const int er = (lane >> 4) * 4;
    const int ec = lane & 15;
    #pragma unroll
    for (int j = 0; j < 4; ++j) {
        int col = bn + wn + j * 16 + ec;
        float bj = (!F16_OUT && bias) ? bias[col] : 0.f;
        #pragma unroll
        for (int i = 0; i < 8; ++i) {
            int rowb = bm + wm + i * 16 + er;
            #pragma unroll
            for (int r = 0; r < 4; ++r) {
                if (F16_OUT)
                    ((_Float16*)Cv)[(size_t)(rowb + r) * ldc + col] =
                        (_Float16)acc[i][j][r];
                else
                    ((float*)Cv)[(size_t)(rowb + r) * ldc + col] =
                        acc[i][j][r] + bj;
            }
        }
    }
}

// ---------------------------------------------------------------------------
// x fp32 -> f16, grid-stride, 8 elems/thread/iter.
// ---------------------------------------------------------------------------
__global__ __launch_bounds__(256) void cvt_to_f16(
    const float* __restrict__ src, _Float16* __restrict__ dst)
{
    const size_t stride = (size_t)gridDim.x * 256 * 8;
    size_t i = ((size_t)blockIdx.x * 256 + threadIdx.x) * 8;
    #pragma unroll 2
    for (; i < (size_t)M_TOT * DREC; i += stride) {
        float4 a = *(const float4*)(src + i);
        float4 b = *(const float4*)(src + i + 4);
        half8 h;
        h[0] = (_Float16)a.x; h[1] = (_Float16)a.y;
        h[2] = (_Float16)a.z; h[3] = (_Float16)a.w;
        h[4] = (_Float16)b.x; h[5] = (_Float16)b.y;
        h[6] = (_Float16)b.z; h[7] = (_Float16)b.w;
        *(half8*)(dst + i) = h;
    }
}

// ---------------------------------------------------------------------------
// W[K,N] fp32 -> T[N,K] f16 (transpose + convert), 32x32 LDS tiles.
// ---------------------------------------------------------------------------
__global__ __launch_bounds__(256) void transpose_cvt(
    const float* __restrict__ W, int K, int N, _Float16* __restrict__ T)
{
    __shared__ float tile[32][33];
    const int k0 = blockIdx.y * 32, n0 = blockIdx.x * 32;
    const int tx = threadIdx.x & 31, ty = threadIdx.x >> 5;  // ty 0..7
    #pragma unroll
    for (int r = 0; r < 32; r += 8)
        tile[ty + r][tx] = W[(size_t)(k0 + ty + r) * N + n0 + tx];
    __syncthreads();
    #pragma unroll
    for (int r = 0; r < 32; r += 8)
        T[(size_t)(n0 + ty + r) * K + k0 + tx] = (_Float16)tile[tx][ty + r];
}

// ---------------------------------------------------------------------------
// Pass A (fused gates + intra scan, summaries only).
// One thread per (b,chunk,d4), 4 channels (d4 = r8-measured config; d8
// regressed, r11). Distance-2 software pipeline; scan kept in log2 domain.
// ---------------------------------------------------------------------------
__global__ __launch_bounds__(256) void scan_chunks(
    const _Float16* __restrict__ aivh, const float* __restrict__ decay_bias,
    float* __restrict__ ctd, float* __restrict__ cfs)
{
    int g  = blockIdx.x * 256 + threadIdx.x;   // < 4*128*256
    int d4 = g & 255;
    int bc = g >> 8;                            // b*128 + chunk

    const _Float16* base =
        aivh + ((size_t)bc * CHUNK) * 3072 + (size_t)d4 * 4;
    float4 db4 = *(const float4*)&decay_bias[d4 * 4];
    float db[4] = {db4.x, db4.y, db4.z, db4.w};

    float cl2[4] = {0, 0, 0, 0}, cw[4] = {0, 0, 0, 0};

    auto step = [&](half4 ap, half4 ip, half4 vv) {
        #pragma unroll
        for (int e = 0; e < 4; ++e) {
            float a  = fast_sigmoid((float)ap[e] + db[e]);
            float ii = fast_sigmoid((float)ip[e]);
            float s  = __builtin_amdgcn_sqrtf(fmaxf(1.f - a * a, 1e-8f))
                       * (ii * (float)vv[e]);
            cl2[e] += __builtin_amdgcn_logf(fmaxf(a, 1e-10f));
            float inv = __builtin_amdgcn_exp2f(fminf(-cl2[e], NLOG2EPS));
            cw[e] += s * inv;
        }
    };

    #define LDROW(ap,ip,vv,T) { const _Float16* q = base + (size_t)(T) * 3072; \
        ap = *(const half4*)q; ip = *(const half4*)(q + 1024);                  \
        vv = *(const half4*)(q + 2048); }

    half4 a0, i0, v0, a1, i1, v1;
    LDROW(a0, i0, v0, 0);
    LDROW(a1, i1, v1, 1);
    for (int t = 0; t < CHUNK - 2; t += 2) {
        half4 a2, i2, v2, a3, i3, v3;
        LDROW(a2, i2, v2, t + 2);
        LDROW(a3, i3, v3, t + 3);
        step(a0, i0, v0);
        step(a1, i1, v1);
        a0 = a2; i0 = i2; v0 = v2;
        a1 = a3; i1 = i3; v1 = v3;
    }
    step(a0, i0, v0);
    step(a1, i1, v1);

    float cd[4];
    #pragma unroll
    for (int e = 0; e < 4; ++e) cd[e] = __builtin_amdgcn_exp2f(cl2[e]);

    size_t so = (size_t)bc * 1024 + (size_t)d4 * 4;
    *(float4*)&ctd[so] = make_float4(cd[0], cd[1], cd[2], cd[3]);
    *(float4*)&cfs[so] = make_float4(cd[0] * cw[0], cd[1] * cw[1],
                                     cd[2] * cw[2], cd[3] * cw[3]);
}

// ---------------------------------------------------------------------------
// Inter-chunk scan: per (b,d), 128 chunk steps, log2 domain, distance-2
// prefetch. 64-thread blocks to spread the 4096 threads over 64 CUs.
// ---------------------------------------------------------------------------
__global__ __launch_bounds__(64) void scan_inter(
    const float* __restrict__ ctd, const float* __restrict__ cfs,
    float* __restrict__ incoming)
{
    int g = blockIdx.x * 64 + threadIdx.x;   // < 4*1024
    int d = g & 1023;
    int b = g >> 10;

    const size_t base = (size_t)b * NCHUNK * 1024 + (size_t)d;
    float cum2 = 0.f, cwc = 0.f;
    float pccd = 1.f, pcwc = 0.f;

    float t0 = ctd[base], f0 = cfs[base];
    float t1 = ctd[base + 1024], f1 = cfs[base + 1024];
    for (int n = 0; n < NCHUNK - 2; n += 2) {
        float t2 = ctd[base + (size_t)(n + 2) * 1024];
        float f2 = cfs[base + (size_t)(n + 2) * 1024];
        float t3 = ctd[base + (size_t)(n + 3) * 1024];
        float f3 = cfs[base + (size_t)(n + 3) * 1024];

        incoming[base + (size_t)n * 1024] = (n == 0) ? 0.f : pccd * pcwc;
        cum2 += __builtin_amdgcn_logf(fmaxf(t0, 1e-10f));
        float ccd = __builtin_amdgcn_exp2f(cum2);
        cwc += f0 * __builtin_amdgcn_exp2f(fminf(-cum2, NLOG2EPS));
        pccd = ccd; pcwc = cwc;

        incoming[base + (size_t)(n + 1) * 1024] = pccd * pcwc;
        cum2 += __builtin_amdgcn_logf(fmaxf(t1, 1e-10f));
        ccd = __builtin_amdgcn_exp2f(cum2);
        cwc += f1 * __builtin_amdgcn_exp2f(fminf(-cum2, NLOG2EPS));
        pccd = ccd; pcwc = cwc;

        t0 = t2; f0 = f2; t1 = t3; f1 = f3;
    }
    incoming[base + (size_t)(NCHUNK - 2) * 1024] = pccd * pcwc;
    cum2 += __builtin_amdgcn_logf(fmaxf(t0, 1e-10f));
    pccd = __builtin_amdgcn_exp2f(cum2);
    cwc += f0 * __builtin_amdgcn_exp2f(fminf(-cum2, NLOG2EPS));
    pcwc = cwc;
    incoming[base + (size_t)(NCHUNK - 1) * 1024] = pccd * pcwc;
}

// ---------------------------------------------------------------------------
// Pass C (fused gates + intra scan + combine), same pipeline as Pass A;
// writes h = cd*(cw+inc) as f16 into compact hb[M_TOT,1024].
// ---------------------------------------------------------------------------
__global__ __launch_bounds__(256) void scan_apply(
    const _Float16* __restrict__ aivh, const float* __restrict__ decay_bias,
    const float* __restrict__ incoming, _Float16* __restrict__ hb)
{
    int g  = blockIdx.x * 256 + threadIdx.x;   // < 4*128*256
    int d4 = g & 255;
    int bc = g >> 8;

    const _Float16* base =
        aivh + ((size_t)bc * CHUNK) * 3072 + (size_t)d4 * 4;
    _Float16* hbase = hb + ((size_t)bc * CHUNK) * 1024 + (size_t)d4 * 4;
    float4 db4 = *(const float4*)&decay_bias[d4 * 4];
    float db[4] = {db4.x, db4.y, db4.z, db4.w};
    float4 ic4 = *(const float4*)&incoming[(size_t)bc * 1024 + d4 * 4];
    float inc[4] = {ic4.x, ic4.y, ic4.z, ic4.w};

    float cl2[4] = {0, 0, 0, 0}, cw[4] = {0, 0, 0, 0};

    auto step = [&](half4 ap, half4 ip, half4 vv, int t) {
        half4 h;
        #pragma unroll
        for (int e = 0; e < 4; ++e) {
            float a  = fast_sigmoid((float)ap[e] + db[e]);
            float ii = fast_sigmoid((float)ip[e]);
            float s  = __builtin_amdgcn_sqrtf(fmaxf(1.f - a * a, 1e-8f))
                       * (ii * (float)vv[e]);
            cl2[e] += __builtin_amdgcn_logf(fmaxf(a, 1e-10f));
            float inv = __builtin_amdgcn_exp2f(fminf(-cl2[e], NLOG2EPS));
            cw[e] += s * inv;
            float cd = __builtin_amdgcn_exp2f(cl2[e]);
            h[e] = (_Float16)(cd * (cw[e] + inc[e]));
        }
        *(half4*)&hbase[(size_t)t * 1024] = h;
    };

    half4 a0, i0, v0, a1, i1, v1;
    LDROW(a0, i0, v0, 0);
    LDROW(a1, i1, v1, 1);
    for (int t = 0; t < CHUNK - 2; t += 2) {
        half4 a2, i2, v2, a3, i3, v3;
        LDROW(a2, i2, v2, t + 2);
        LDROW(a3, i3, v3, t + 3);
        step(a0, i0, v0, t);
        step(a1, i1, v1, t + 1);
        a0 = a2; i0 = i2; v0 = v2;
        a1 = a3; i1 = i3; v1 = v3;
    }
    step(a0, i0, v0, CHUNK - 2);
    step(a1, i1, v1, CHUNK - 1);
}

// ---------------------------------------------------------------------------
extern "C" void kernel_launch(void* const* d_in, const int* in_sizes, int n_in,
                              void* d_out, int out_size, void* d_ws, size_t ws_size,
                              hipStream_t stream)
{
    const float* x          = (const float*)d_in[0];  // (4,8192,1024)
    const float* W_aiv      = (const float*)d_in[1];  // (1024,3072)
    const float* decay_bias = (const float*)d_in[2];  // (1024,)
    const float* W_mix      = (const float*)d_in[3];  // (1024,1024)
    const float* b_mix      = (const float*)d_in[4];  // (1024,)
    float* out = (float*)d_out;                       // (4,8192,1024) fp32

    _Float16* aivh  = (_Float16*)d_ws;
    _Float16* xh    = aivh + (size_t)M_TOT * N_AIV;
    float* ctd      = (float*)(xh + (size_t)M_TOT * DREC);
    float* cfs      = ctd + (size_t)BATCH * NCHUNK * DREC;
    float* incoming = cfs + (size_t)BATCH * NCHUNK * DREC;
    _Float16* wT    = (_Float16*)(incoming + (size_t)BATCH * NCHUNK * DREC);
    _Float16* mT    = wT + (size_t)N_AIV * DREC;
    _Float16* hb    = xh;   // alias: xh dead after GEMM1

    // 0) conversions (x -> f16; weights -> transposed f16)
    cvt_to_f16<<<2048, 256, 0, stream>>>(x, xh);
    {
        dim3 g1(N_AIV / 32, DREC / 32);
        transpose_cvt<<<g1, 256, 0, stream>>>(W_aiv, DREC, N_AIV, wT);
        dim3 g2(DREC / 32, DREC / 32);
        transpose_cvt<<<g2, 256, 0, stream>>>(W_mix, DREC, DREC, mT);
    }
    // 1) aivh = xh @ W_aiv   (pure-f16 MFMA, f16 output)
    {
        dim3 grid(N_AIV / BN, M_TOT / BM);   // (12, 128) = 1536 blocks
        gemm_ff<true><<<grid, 512, 0, stream>>>(xh, DREC, wT, DREC,
                                                aivh, N_AIV, DREC, nullptr);
    }
    // 2) fused gates + intra scan -> chunk summaries (d4, 512 blocks)
    scan_chunks<<<(BATCH * NCHUNK * 256) / 256, 256, 0, stream>>>(
        aivh, decay_bias, ctd, cfs);
    // 3) inter-chunk scan
    scan_inter<<<(BATCH * DREC) / 64, 64, 0, stream>>>(ctd, cfs, incoming);
    // 4) fused gates + intra scan + combine -> hb (f16, compact; d4)
    scan_apply<<<(BATCH * NCHUNK * 256) / 256, 256, 0, stream>>>(
        aivh, decay_bias, incoming, hb);
    // 5) out = hb @ W_mix + b_mix  (pure-f16 MFMA, fp32 output)
    {
        dim3 grid(DREC / BN, M_TOT / BM);    // (4, 128) = 512 blocks
        gemm_ff<false><<<grid, 512, 0, stream>>>(hb, DREC, mT, DREC,
                                                 out, DREC, DREC, b_mix);
    }
}